// Round 2
// baseline (17262.625 us; speedup 1.0000x reference)
//
#include <hip/hip_runtime.h>
#include <math.h>

#define HD 256
#define BATCH 1024
#define NSTEPS 64
#define DIN 4
#define MMETA 4

#define F(x) ((float)(x))
#define A21f F(0.2)
#define A31f F(3.0/40.0)
#define A32f F(9.0/40.0)
#define A41f F(44.0/45.0)
#define A42f F(-56.0/15.0)
#define A43f F(32.0/9.0)
#define A51f F(19372.0/6561.0)
#define A52f F(-25360.0/2187.0)
#define A53f F(64448.0/6561.0)
#define A54f F(-212.0/729.0)
#define A61f F(9017.0/3168.0)
#define A62f F(-355.0/33.0)
#define A63f F(46732.0/5247.0)
#define A64f F(49.0/176.0)
#define A65f F(-5103.0/18656.0)
#define BC0f F(35.0/384.0)
#define BC2f F(500.0/1113.0)
#define BC3f F(125.0/192.0)
#define BC4f F(-2187.0/6784.0)
#define BC5f F(11.0/84.0)
#define EC0f F(35.0/384.0 - 5179.0/57600.0)
#define EC2f F(500.0/1113.0 - 7571.0/16695.0)
#define EC3f F(125.0/192.0 - 393.0/640.0)
#define EC4f F(-2187.0/6784.0 + 92097.0/339200.0)
#define EC5f F(11.0/84.0 - 187.0/2100.0)
#define EC6f F(-1.0/40.0)

#define SELU_SCALE 1.0507009873554805f
#define SELU_ALPHA 1.6732632423543772f

// ---------------- generic transpose: in[R][C] -> out[C][R] ----------------
__global__ void transpose_kernel(const float* __restrict__ in, float* __restrict__ out,
                                 int R, int C) {
    int c = blockIdx.x * 256 + threadIdx.x;
    int r = blockIdx.y;
    if (c < C) out[c * R + r] = in[r * C + c];
}

// ---------------- ODE partial dot: 64 k-values, 4 batch elements ----------
// wp = WT + L*65536 + k0*HD + row  (WT is [k][row] transposed layout)
__device__ __forceinline__ void partial4(const float* __restrict__ wp,
                                         const float (*zsh)[4], int k0,
                                         float (&acc)[4]) {
    float wA[8], wB[8];
#pragma unroll
    for (int u = 0; u < 8; ++u) wA[u] = wp[u * HD];
#pragma unroll
    for (int u = 0; u < 8; ++u) wB[u] = wp[(8 + u) * HD];
    acc[0] = 0.f; acc[1] = 0.f; acc[2] = 0.f; acc[3] = 0.f;
#pragma unroll
    for (int kb = 0; kb < 64; kb += 8) {
        float wC[8];
        if (kb < 48) {
#pragma unroll
            for (int u = 0; u < 8; ++u) wC[u] = wp[(kb + 16 + u) * HD];
        }
#pragma unroll
        for (int u = 0; u < 8; ++u) {
            const float4 z4 = *(const float4*)(&zsh[k0 + kb + u][0]);
            const float w = wA[u];
            acc[0] = fmaf(w, z4.x, acc[0]);
            acc[1] = fmaf(w, z4.y, acc[1]);
            acc[2] = fmaf(w, z4.z, acc[2]);
            acc[3] = fmaf(w, z4.w, acc[3]);
        }
#pragma unroll
        for (int u = 0; u < 8; ++u) { wA[u] = wB[u]; if (kb < 48) wB[u] = wC[u]; }
    }
}

// 4-layer MLP eval. Caller has written zsh and barriered. Returns this thread's
// own output value (row, g=q). No trailing barrier (caller fuses z-write + barrier).
__device__ __forceinline__ float eval_f(const float* __restrict__ WTb,
                                        const float (&bset)[4],
                                        int row, int q,
                                        float (*zsh)[4],
                                        float (*psum)[4][HD]) {
    float v = 0.f;
#pragma unroll
    for (int L = 0; L < 4; ++L) {
        float acc[4];
        partial4(WTb + L * 65536 + q * 64 * HD + row, zsh, q * 64, acc);
#pragma unroll
        for (int g = 0; g < 4; ++g) psum[q][g][row] = acc[g];
        __syncthreads();
        v = ((psum[0][q][row] + psum[1][q][row]) + (psum[2][q][row] + psum[3][q][row])) + bset[L];
        if (L < 3) {
            float a = v > 0.f ? SELU_SCALE * v : SELU_SCALE * SELU_ALPHA * expm1f(v);
            zsh[row][q] = a;
            __syncthreads();
        }
    }
    return v;
}

// ---------------- GRU: 256 blocks (G=4), 1024 threads ----------------
__global__ __launch_bounds__(1024, 4) void gru_kernel(
    const float* __restrict__ x, const float* __restrict__ meta,
    const float* __restrict__ WihT, const float* __restrict__ WhhT,
    const float* __restrict__ bih, const float* __restrict__ bhh,
    float* __restrict__ h_out) {
    __shared__ float hsh[HD][4];     // [k][g] for b128 broadcast reads
    __shared__ float xmsh[8][4];
    __shared__ float gsa[4][768];    // [g][gate_row] combined (r,z) / inn
    __shared__ float gsb[4][HD];     // [g][row] hn part for n-gate

    const int tid = threadIdx.x;
    const int row = tid & 255;
    const int g   = tid >> 8;
    const int b0  = blockIdx.x * 4;
    const int gr  = tid;             // gate row if < 768

    float bi = 0.f, bh = 0.f;
    if (gr < 768) { bi = bih[gr]; bh = bhh[gr]; }

    float h_own = 0.f;
    hsh[row][g] = 0.f;

    for (int n = 0; n < NSTEPS; ++n) {
        if (tid < 32) {
            int c = tid & 7, gg = tid >> 3;
            xmsh[c][gg] = (c < 4) ? x[((b0 + gg) * NSTEPS + n) * DIN + c]
                                  : meta[(b0 + gg) * MMETA + (c - 4)];
        }
        __syncthreads();   // xm + hsh ready

        if (gr < 768) {
            float ai[4], ah[4];
#pragma unroll
            for (int gg = 0; gg < 4; ++gg) { ai[gg] = bi; ah[gg] = bh; }
#pragma unroll
            for (int c = 0; c < 8; ++c) {
                float w = WihT[c * 768 + gr];
                const float4 x4 = *(const float4*)(&xmsh[c][0]);
                ai[0] = fmaf(w, x4.x, ai[0]); ai[1] = fmaf(w, x4.y, ai[1]);
                ai[2] = fmaf(w, x4.z, ai[2]); ai[3] = fmaf(w, x4.w, ai[3]);
            }
            {
                const float* wp = WhhT + gr;
                float wA[8], wB[8];
#pragma unroll
                for (int u = 0; u < 8; ++u) wA[u] = wp[u * 768];
#pragma unroll
                for (int u = 0; u < 8; ++u) wB[u] = wp[(8 + u) * 768];
#pragma unroll
                for (int kb = 0; kb < HD; kb += 8) {
                    float wC[8];
                    if (kb < HD - 16) {
#pragma unroll
                        for (int u = 0; u < 8; ++u) wC[u] = wp[(kb + 16 + u) * 768];
                    }
#pragma unroll
                    for (int u = 0; u < 8; ++u) {
                        const float4 h4 = *(const float4*)(&hsh[kb + u][0]);
                        const float w = wA[u];
                        ah[0] = fmaf(w, h4.x, ah[0]); ah[1] = fmaf(w, h4.y, ah[1]);
                        ah[2] = fmaf(w, h4.z, ah[2]); ah[3] = fmaf(w, h4.w, ah[3]);
                    }
#pragma unroll
                    for (int u = 0; u < 8; ++u) { wA[u] = wB[u]; if (kb < HD - 16) wB[u] = wC[u]; }
                }
            }
            if (gr < 512) {
#pragma unroll
                for (int gg = 0; gg < 4; ++gg) gsa[gg][gr] = ai[gg] + ah[gg];
            } else {
#pragma unroll
                for (int gg = 0; gg < 4; ++gg) { gsa[gg][gr] = ai[gg]; gsb[gg][gr - 512] = ah[gg]; }
            }
        }
        __syncthreads();   // gates ready; all hsh/xm reads done

        {
            float av  = gsa[g][row];
            float zv  = gsa[g][row + 256];
            float niv = gsa[g][row + 512];
            float nhv = gsb[g][row];
            float rr = 1.f / (1.f + expf(-av));
            float zz = 1.f / (1.f + expf(-zv));
            float nn = tanhf(niv + rr * nhv);
            h_own = (1.f - zz) * nn + zz * h_own;
            hsh[row][g] = h_own;
        }
        // next-iteration top barrier orders hsh writes vs matvec reads
    }
    h_out[(b0 + g) * HD + row] = h_own;
}

// ---------------- encoder + reparameterization (unchanged, G=8) ----------
__global__ __launch_bounds__(256) void enc_kernel(
    const float* __restrict__ h_buf, const float* __restrict__ eps,
    const float* __restrict__ W1T, const float* __restrict__ b1,
    const float* __restrict__ W2T, const float* __restrict__ b2,
    float* __restrict__ y0_buf) {
    __shared__ float zsh[HD][8];
    const int tid = threadIdx.x;
    const int b0 = blockIdx.x * 8;
#pragma unroll
    for (int g = 0; g < 8; ++g) zsh[tid][g] = h_buf[(b0 + g) * HD + tid];
    __syncthreads();
    float acc[8];
    {
        float bb = b1[tid];
#pragma unroll
        for (int g = 0; g < 8; ++g) acc[g] = bb;
        for (int k = 0; k < HD; k += 4) {
#pragma unroll
            for (int u = 0; u < 4; ++u) {
                float w = W1T[(k + u) * HD + tid];
                const float4 za = *(const float4*)(&zsh[k + u][0]);
                const float4 zb = *(const float4*)(&zsh[k + u][4]);
                acc[0] = fmaf(w, za.x, acc[0]); acc[1] = fmaf(w, za.y, acc[1]);
                acc[2] = fmaf(w, za.z, acc[2]); acc[3] = fmaf(w, za.w, acc[3]);
                acc[4] = fmaf(w, zb.x, acc[4]); acc[5] = fmaf(w, zb.y, acc[5]);
                acc[6] = fmaf(w, zb.z, acc[6]); acc[7] = fmaf(w, zb.w, acc[7]);
            }
        }
    }
    __syncthreads();
#pragma unroll
    for (int g = 0; g < 8; ++g) zsh[tid][g] = fmaxf(acc[g], 0.f);
    __syncthreads();
    float am[8], as[8];
    {
        float bm = b2[tid], bs = b2[tid + HD];
#pragma unroll
        for (int g = 0; g < 8; ++g) { am[g] = bm; as[g] = bs; }
        for (int k = 0; k < HD; k += 4) {
#pragma unroll
            for (int u = 0; u < 4; ++u) {
                float wm = W2T[(k + u) * 512 + tid];
                float ws2 = W2T[(k + u) * 512 + HD + tid];
                const float4 za = *(const float4*)(&zsh[k + u][0]);
                const float4 zb = *(const float4*)(&zsh[k + u][4]);
                am[0] = fmaf(wm, za.x, am[0]); am[1] = fmaf(wm, za.y, am[1]);
                am[2] = fmaf(wm, za.z, am[2]); am[3] = fmaf(wm, za.w, am[3]);
                am[4] = fmaf(wm, zb.x, am[4]); am[5] = fmaf(wm, zb.y, am[5]);
                am[6] = fmaf(wm, zb.z, am[6]); am[7] = fmaf(wm, zb.w, am[7]);
                as[0] = fmaf(ws2, za.x, as[0]); as[1] = fmaf(ws2, za.y, as[1]);
                as[2] = fmaf(ws2, za.z, as[2]); as[3] = fmaf(ws2, za.w, as[3]);
                as[4] = fmaf(ws2, zb.x, as[4]); as[5] = fmaf(ws2, zb.y, as[5]);
                as[6] = fmaf(ws2, zb.z, as[6]); as[7] = fmaf(ws2, zb.w, as[7]);
            }
        }
    }
#pragma unroll
    for (int g = 0; g < 8; ++g)
        y0_buf[(b0 + g) * HD + tid] = eps[(b0 + g) * HD + tid] * as[g] + am[g];
}

// ---------------- dopri5: 256 blocks (G=4), 1024 threads ----------------
__global__ __launch_bounds__(1024, 4) void ode_kernel(
    const float* __restrict__ y0_buf, const float* __restrict__ times,
    const float* __restrict__ doses, const float* __restrict__ WT,
    const float* __restrict__ ob1, const float* __restrict__ ob2,
    const float* __restrict__ ob3, const float* __restrict__ ob4,
    const float* __restrict__ meta, const float* __restrict__ fcW,
    const float* __restrict__ fcb, float* __restrict__ out) {
    __shared__ float zsh[HD][4];       // [k][g]
    __shared__ float psum[4][4][HD];   // [kq][g][row]
    __shared__ float redsh[4][4];      // [g][wave-in-group]
    __shared__ float actflag[4];

    const int tid = threadIdx.x;
    const int row = tid & 255;
    const int q   = tid >> 8;          // k-quad in partial phase; g for state ownership
    const int b0  = blockIdx.x * 4;
    const int bidx = b0 + q;

    float bset[4];
    bset[0] = ob1[row]; bset[1] = ob2[row]; bset[2] = ob3[row]; bset[3] = ob4[row];

    float y_own = y0_buf[bidx * HD + row];

    for (int j = 0; j < 4; ++j) {
        const float tt0 = times[((j * BATCH) + bidx) * 2 + 0];
        const float t1  = times[((j * BATCH) + bidx) * 2 + 1];
        const float ds  = doses[j * BATCH + bidx];
        const bool act0 = tt0 < t1;
        const float ysv = y_own;
        y_own += ds;
        float t_s = tt0;
        float dt_s = fmaxf(t1 - tt0, 1e-6f) * 0.1f;
        bool act_s = t_s < t1;

        zsh[row][q] = y_own;
        if (row == 0) actflag[q] = act_s ? 1.f : 0.f;
        __syncthreads();
        bool anyact = (actflag[0] + actflag[1] + actflag[2] + actflag[3]) > 0.f;

        float k1 = 0.f, k2, k3, k4, k5, k6, k7, y5;
        if (anyact) k1 = eval_f(WT, bset, row, q, zsh, psum);   // FSAL seed

        for (int step = 0; step < 32 && anyact; ++step) {
            act_s = t_s < t1;
            // NaN-propagating clip (matches jnp semantics)
            float d = dt_s;
            if (d < 0.f) d = 0.f;
            float rem = t1 - t_s;
            if (rem < 0.f) rem = 0.f;
            if (d > rem) d = rem;

            zsh[row][q] = y_own + d * (A21f * k1);
            __syncthreads();
            k2 = eval_f(WT, bset, row, q, zsh, psum);
            zsh[row][q] = y_own + d * (A31f * k1 + A32f * k2);
            __syncthreads();
            k3 = eval_f(WT, bset, row, q, zsh, psum);
            zsh[row][q] = y_own + d * (A41f * k1 + A42f * k2 + A43f * k3);
            __syncthreads();
            k4 = eval_f(WT, bset, row, q, zsh, psum);
            zsh[row][q] = y_own + d * (A51f * k1 + A52f * k2 + A53f * k3 + A54f * k4);
            __syncthreads();
            k5 = eval_f(WT, bset, row, q, zsh, psum);
            zsh[row][q] = y_own + d * (A61f * k1 + A62f * k2 + A63f * k3 + A64f * k4 + A65f * k5);
            __syncthreads();
            k6 = eval_f(WT, bset, row, q, zsh, psum);
            y5 = y_own + d * (BC0f * k1 + BC2f * k3 + BC3f * k4 + BC4f * k5 + BC5f * k6);
            zsh[row][q] = y5;
            __syncthreads();
            k7 = eval_f(WT, bset, row, q, zsh, psum);

            float err = d * (EC0f * k1 + EC2f * k3 + EC3f * k4 + EC4f * k5 + EC5f * k6 + EC6f * k7);
            float sc = 1e-6f + 1e-3f * fmaxf(fabsf(y_own), fabsf(y5));
            float r = err / sc;
            float s = r * r;
#pragma unroll
            for (int off = 32; off; off >>= 1) s += __shfl_xor(s, off, 64);
            if ((tid & 63) == 0) redsh[q][(tid >> 6) & 3] = s;
            __syncthreads();
            float en = sqrtf(((redsh[q][0] + redsh[q][1]) + (redsh[q][2] + redsh[q][3])) * (1.0f / HD));
            bool accg = (en <= 1.0f) && act_s;
            if (accg) { y_own = y5; t_s = t_s + d; k1 = k7; }   // FSAL carry
            float fac = 0.9f * powf(en + 1e-10f, -0.2f);
            if (fac < 0.2f) fac = 0.2f;
            if (fac > 10.f) fac = 10.f;
            if (act_s) dt_s = fmaxf(d, 1e-8f) * fac;
            bool act_n = t_s < t1;
            if (row == 0) actflag[q] = act_n ? 1.f : 0.f;
            __syncthreads();
            anyact = (actflag[0] + actflag[1] + actflag[2] + actflag[3]) > 0.f;
        }
        y_own = act0 ? y_own : ysv;
    }

    // final FC: out[b] = y . fcW[0:256] + meta . fcW[256:260] + fcb
    float part = y_own * fcW[row];
#pragma unroll
    for (int off = 32; off; off >>= 1) part += __shfl_xor(part, off, 64);
    if ((tid & 63) == 0) redsh[q][(tid >> 6) & 3] = part;
    __syncthreads();
    if (row == 0) {
        float v = (redsh[q][0] + redsh[q][1]) + (redsh[q][2] + redsh[q][3]);
#pragma unroll
        for (int m = 0; m < MMETA; ++m) v += meta[bidx * MMETA + m] * fcW[HD + m];
        out[bidx] = v + fcb[0];
    }
}

extern "C" void kernel_launch(void* const* d_in, const int* in_sizes, int n_in,
                              void* d_out, int out_size, void* d_ws, size_t ws_size,
                              hipStream_t stream) {
    const float* x     = (const float*)d_in[0];
    const float* meta  = (const float*)d_in[1];
    const float* eps   = (const float*)d_in[2];
    const float* times = (const float*)d_in[3];
    const float* doses = (const float*)d_in[4];
    const float* Wih   = (const float*)d_in[5];
    const float* Whh   = (const float*)d_in[6];
    const float* bih   = (const float*)d_in[7];
    const float* bhh   = (const float*)d_in[8];
    const float* eW1   = (const float*)d_in[9];
    const float* eb1   = (const float*)d_in[10];
    const float* eW2   = (const float*)d_in[11];
    const float* eb2   = (const float*)d_in[12];
    const float* oW1   = (const float*)d_in[13];
    const float* ob1   = (const float*)d_in[14];
    const float* oW2   = (const float*)d_in[15];
    const float* ob2   = (const float*)d_in[16];
    const float* oW3   = (const float*)d_in[17];
    const float* ob3   = (const float*)d_in[18];
    const float* oW4   = (const float*)d_in[19];
    const float* ob4   = (const float*)d_in[20];
    const float* fcW   = (const float*)d_in[21];
    const float* fcb   = (const float*)d_in[22];

    float* ws   = (float*)d_ws;
    float* WihT = ws;             // [8][768]      6144
    float* WhhT = WihT + 6144;    // [256][768]    196608
    float* eW1T = WhhT + 196608;  // [256][256]    65536
    float* eW2T = eW1T + 65536;   // [256][512]    131072
    float* oWT  = eW2T + 131072;  // [4][256][256] 262144
    float* hbuf = oWT + 262144;   // [1024][256]   262144
    float* y0b  = hbuf + 262144;  // [1024][256]   262144

    transpose_kernel<<<dim3(1, 768), 256, 0, stream>>>(Wih, WihT, 768, 8);
    transpose_kernel<<<dim3(1, 768), 256, 0, stream>>>(Whh, WhhT, 768, 256);
    transpose_kernel<<<dim3(1, 256), 256, 0, stream>>>(eW1, eW1T, 256, 256);
    transpose_kernel<<<dim3(1, 512), 256, 0, stream>>>(eW2, eW2T, 512, 256);
    transpose_kernel<<<dim3(1, 256), 256, 0, stream>>>(oW1, oWT, 256, 256);
    transpose_kernel<<<dim3(1, 256), 256, 0, stream>>>(oW2, oWT + 65536, 256, 256);
    transpose_kernel<<<dim3(1, 256), 256, 0, stream>>>(oW3, oWT + 131072, 256, 256);
    transpose_kernel<<<dim3(1, 256), 256, 0, stream>>>(oW4, oWT + 196608, 256, 256);

    gru_kernel<<<BATCH / 4, 1024, 0, stream>>>(x, meta, WihT, WhhT, bih, bhh, hbuf);
    enc_kernel<<<BATCH / 8, 256, 0, stream>>>(hbuf, eps, eW1T, eb1, eW2T, eb2, y0b);
    ode_kernel<<<BATCH / 4, 1024, 0, stream>>>(y0b, times, doses, oWT, ob1, ob2, ob3, ob4,
                                               meta, fcW, fcb, (float*)d_out);
}

// Round 3
// 2708.031 us; speedup vs baseline: 6.3746x; 6.3746x over previous
//
#include <hip/hip_runtime.h>
#include <math.h>

#define HD 256
#define BATCH 1024
#define NSTEPS 64
#define DIN 4
#define MMETA 4

#define F(x) ((float)(x))
#define A21f F(0.2)
#define A31f F(3.0/40.0)
#define A32f F(9.0/40.0)
#define A41f F(44.0/45.0)
#define A42f F(-56.0/15.0)
#define A43f F(32.0/9.0)
#define A51f F(19372.0/6561.0)
#define A52f F(-25360.0/2187.0)
#define A53f F(64448.0/6561.0)
#define A54f F(-212.0/729.0)
#define A61f F(9017.0/3168.0)
#define A62f F(-355.0/33.0)
#define A63f F(46732.0/5247.0)
#define A64f F(49.0/176.0)
#define A65f F(-5103.0/18656.0)
#define BC0f F(35.0/384.0)
#define BC2f F(500.0/1113.0)
#define BC3f F(125.0/192.0)
#define BC4f F(-2187.0/6784.0)
#define BC5f F(11.0/84.0)
#define EC0f F(35.0/384.0 - 5179.0/57600.0)
#define EC2f F(500.0/1113.0 - 7571.0/16695.0)
#define EC3f F(125.0/192.0 - 393.0/640.0)
#define EC4f F(-2187.0/6784.0 + 92097.0/339200.0)
#define EC5f F(11.0/84.0 - 187.0/2100.0)
#define EC6f F(-1.0/40.0)

#define SELU_SCALE 1.0507009873554805f
#define SELU_ALPHA 1.6732632423543772f

// ---------------- generic transpose: in[R][C] -> out[C][R] ----------------
__global__ void transpose_kernel(const float* __restrict__ in, float* __restrict__ out,
                                 int R, int C) {
    int c = blockIdx.x * 256 + threadIdx.x;
    int r = blockIdx.y;
    if (c < C) out[c * R + r] = in[r * C + c];
}

// ---------------- ODE partial dot: 128 k-values, 4 batch elems ------------
// wp = WT + L*65536 + khalf*128*HD + row  (WT layout: [k][out_row])
__device__ __forceinline__ void partial128(const float* __restrict__ wp,
                                           const float (*zsh)[4], int k0,
                                           float (&acc)[4]) {
    float wA[8], wB[8];
#pragma unroll
    for (int u = 0; u < 8; ++u) wA[u] = wp[u * HD];
#pragma unroll
    for (int u = 0; u < 8; ++u) wB[u] = wp[(8 + u) * HD];
    acc[0] = 0.f; acc[1] = 0.f; acc[2] = 0.f; acc[3] = 0.f;
    for (int kb = 0; kb < 128; kb += 8) {
        float wC[8];
        if (kb < 112) {
#pragma unroll
            for (int u = 0; u < 8; ++u) wC[u] = wp[(kb + 16 + u) * HD];
        }
#pragma unroll
        for (int u = 0; u < 8; ++u) {
            const float4 z4 = *(const float4*)(&zsh[k0 + kb + u][0]);
            const float w = wA[u];
            acc[0] = fmaf(w, z4.x, acc[0]);
            acc[1] = fmaf(w, z4.y, acc[1]);
            acc[2] = fmaf(w, z4.z, acc[2]);
            acc[3] = fmaf(w, z4.w, acc[3]);
        }
#pragma unroll
        for (int u = 0; u < 8; ++u) { wA[u] = wB[u]; if (kb < 112) wB[u] = wC[u]; }
    }
}

// 4-layer MLP eval; thread (row,q) gets outputs for batch elems g=2q, 2q+1.
// Caller has written zsh (all 4 g) and issued a barrier.
__device__ __forceinline__ void eval_f2(const float* __restrict__ WTb,
                                        const float (&bset)[4],
                                        int row, int q,
                                        float (*zsh)[4],
                                        float (*psum)[4][HD],
                                        float (&vout)[2]) {
#pragma unroll
    for (int L = 0; L < 4; ++L) {
        float acc[4];
        partial128(WTb + L * 65536 + q * 128 * HD + row, zsh, q * 128, acc);
        psum[q][0][row] = acc[0];
        psum[q][1][row] = acc[1];
        psum[q][2][row] = acc[2];
        psum[q][3][row] = acc[3];
        __syncthreads();
        float v0 = (psum[0][2 * q][row]     + psum[1][2 * q][row])     + bset[L];
        float v1 = (psum[0][2 * q + 1][row] + psum[1][2 * q + 1][row]) + bset[L];
        if (L < 3) {
            float a0 = v0 > 0.f ? SELU_SCALE * v0 : SELU_SCALE * SELU_ALPHA * expm1f(v0);
            float a1 = v1 > 0.f ? SELU_SCALE * v1 : SELU_SCALE * SELU_ALPHA * expm1f(v1);
            zsh[row][2 * q]     = a0;
            zsh[row][2 * q + 1] = a1;
            __syncthreads();
        } else {
            vout[0] = v0; vout[1] = v1;
        }
    }
}

// ---------------- GRU: 256 blocks (G=4), 768 threads ----------------------
__global__ __launch_bounds__(768, 2) void gru_kernel(
    const float* __restrict__ x, const float* __restrict__ meta,
    const float* __restrict__ WihT, const float* __restrict__ WhhT,
    const float* __restrict__ bih, const float* __restrict__ bhh,
    float* __restrict__ h_out) {
    __shared__ float hsh[HD][4];     // [k][g], b128 broadcast reads
    __shared__ float xmsh[8][4];
    __shared__ float gsa[4][768];    // [g][gate_row]: (r,z) pre-act; [512+]: inn
    __shared__ float gsb[4][HD];     // [g][row]: hn part for n-gate

    const int tid = threadIdx.x;     // gate row 0..767
    const int b0  = blockIdx.x * 4;
    const float bi = bih[tid];
    const float bh = bhh[tid];

    float h_own[4];
    if (tid < HD) {
#pragma unroll
        for (int g = 0; g < 4; ++g) { h_own[g] = 0.f; hsh[tid][g] = 0.f; }
    }

    for (int n = 0; n < NSTEPS; ++n) {
        if (tid < 32) {
            int c = tid & 7, gg = tid >> 3;
            xmsh[c][gg] = (c < 4) ? x[((b0 + gg) * NSTEPS + n) * DIN + c]
                                  : meta[(b0 + gg) * MMETA + (c - 4)];
        }
        __syncthreads();   // xm + hsh ready

        float ai[4], ah[4];
#pragma unroll
        for (int g = 0; g < 4; ++g) { ai[g] = bi; ah[g] = bh; }
#pragma unroll
        for (int c = 0; c < 8; ++c) {
            float w = WihT[c * 768 + tid];
            const float4 x4 = *(const float4*)(&xmsh[c][0]);
            ai[0] = fmaf(w, x4.x, ai[0]); ai[1] = fmaf(w, x4.y, ai[1]);
            ai[2] = fmaf(w, x4.z, ai[2]); ai[3] = fmaf(w, x4.w, ai[3]);
        }
        {
            const float* wp = WhhT + tid;
            float wA[8], wB[8];
#pragma unroll
            for (int u = 0; u < 8; ++u) wA[u] = wp[u * 768];
#pragma unroll
            for (int u = 0; u < 8; ++u) wB[u] = wp[(8 + u) * 768];
            for (int kb = 0; kb < HD; kb += 8) {
                float wC[8];
                if (kb < HD - 16) {
#pragma unroll
                    for (int u = 0; u < 8; ++u) wC[u] = wp[(kb + 16 + u) * 768];
                }
#pragma unroll
                for (int u = 0; u < 8; ++u) {
                    const float4 h4 = *(const float4*)(&hsh[kb + u][0]);
                    const float w = wA[u];
                    ah[0] = fmaf(w, h4.x, ah[0]); ah[1] = fmaf(w, h4.y, ah[1]);
                    ah[2] = fmaf(w, h4.z, ah[2]); ah[3] = fmaf(w, h4.w, ah[3]);
                }
#pragma unroll
                for (int u = 0; u < 8; ++u) { wA[u] = wB[u]; if (kb < HD - 16) wB[u] = wC[u]; }
            }
        }
        if (tid < 512) {
#pragma unroll
            for (int g = 0; g < 4; ++g) gsa[g][tid] = ai[g] + ah[g];
        } else {
#pragma unroll
            for (int g = 0; g < 4; ++g) { gsa[g][tid] = ai[g]; gsb[g][tid - 512] = ah[g]; }
        }
        __syncthreads();   // gates ready; all hsh/xm reads done

        if (tid < HD) {
#pragma unroll
            for (int g = 0; g < 4; ++g) {
                float av  = gsa[g][tid];
                float zv  = gsa[g][tid + 256];
                float niv = gsa[g][tid + 512];
                float nhv = gsb[g][tid];
                float rr = 1.f / (1.f + expf(-av));
                float zz = 1.f / (1.f + expf(-zv));
                float nn = tanhf(niv + rr * nhv);
                h_own[g] = (1.f - zz) * nn + zz * h_own[g];
                hsh[tid][g] = h_own[g];
            }
        }
        // next-iteration top barrier orders hsh writes vs matvec reads
    }
    if (tid < HD) {
#pragma unroll
        for (int g = 0; g < 4; ++g) h_out[(b0 + g) * HD + tid] = h_own[g];
    }
}

// ---------------- encoder + reparameterization (G=8, 128 blocks) ----------
__global__ __launch_bounds__(256) void enc_kernel(
    const float* __restrict__ h_buf, const float* __restrict__ eps,
    const float* __restrict__ W1T, const float* __restrict__ b1,
    const float* __restrict__ W2T, const float* __restrict__ b2,
    float* __restrict__ y0_buf) {
    __shared__ float zsh[HD][8];
    const int tid = threadIdx.x;
    const int b0 = blockIdx.x * 8;
#pragma unroll
    for (int g = 0; g < 8; ++g) zsh[tid][g] = h_buf[(b0 + g) * HD + tid];
    __syncthreads();
    float acc[8];
    {
        float bb = b1[tid];
#pragma unroll
        for (int g = 0; g < 8; ++g) acc[g] = bb;
        for (int k = 0; k < HD; k += 4) {
#pragma unroll
            for (int u = 0; u < 4; ++u) {
                float w = W1T[(k + u) * HD + tid];
                const float4 za = *(const float4*)(&zsh[k + u][0]);
                const float4 zb = *(const float4*)(&zsh[k + u][4]);
                acc[0] = fmaf(w, za.x, acc[0]); acc[1] = fmaf(w, za.y, acc[1]);
                acc[2] = fmaf(w, za.z, acc[2]); acc[3] = fmaf(w, za.w, acc[3]);
                acc[4] = fmaf(w, zb.x, acc[4]); acc[5] = fmaf(w, zb.y, acc[5]);
                acc[6] = fmaf(w, zb.z, acc[6]); acc[7] = fmaf(w, zb.w, acc[7]);
            }
        }
    }
    __syncthreads();
#pragma unroll
    for (int g = 0; g < 8; ++g) zsh[tid][g] = fmaxf(acc[g], 0.f);
    __syncthreads();
    float am[8], as[8];
    {
        float bm = b2[tid], bs = b2[tid + HD];
#pragma unroll
        for (int g = 0; g < 8; ++g) { am[g] = bm; as[g] = bs; }
        for (int k = 0; k < HD; k += 4) {
#pragma unroll
            for (int u = 0; u < 4; ++u) {
                float wm = W2T[(k + u) * 512 + tid];
                float ws2 = W2T[(k + u) * 512 + HD + tid];
                const float4 za = *(const float4*)(&zsh[k + u][0]);
                const float4 zb = *(const float4*)(&zsh[k + u][4]);
                am[0] = fmaf(wm, za.x, am[0]); am[1] = fmaf(wm, za.y, am[1]);
                am[2] = fmaf(wm, za.z, am[2]); am[3] = fmaf(wm, za.w, am[3]);
                am[4] = fmaf(wm, zb.x, am[4]); am[5] = fmaf(wm, zb.y, am[5]);
                am[6] = fmaf(wm, zb.z, am[6]); am[7] = fmaf(wm, zb.w, am[7]);
                as[0] = fmaf(ws2, za.x, as[0]); as[1] = fmaf(ws2, za.y, as[1]);
                as[2] = fmaf(ws2, za.z, as[2]); as[3] = fmaf(ws2, za.w, as[3]);
                as[4] = fmaf(ws2, zb.x, as[4]); as[5] = fmaf(ws2, zb.y, as[5]);
                as[6] = fmaf(ws2, zb.z, as[6]); as[7] = fmaf(ws2, zb.w, as[7]);
            }
        }
    }
#pragma unroll
    for (int g = 0; g < 8; ++g)
        y0_buf[(b0 + g) * HD + tid] = eps[(b0 + g) * HD + tid] * as[g] + am[g];
}

// ---------------- dopri5: 256 blocks (G=4), 512 threads, 2-way k-split ----
__global__ __launch_bounds__(512, 2) void ode_kernel(
    const float* __restrict__ y0_buf, const float* __restrict__ times,
    const float* __restrict__ doses, const float* __restrict__ WT,
    const float* __restrict__ ob1, const float* __restrict__ ob2,
    const float* __restrict__ ob3, const float* __restrict__ ob4,
    const float* __restrict__ meta, const float* __restrict__ fcW,
    const float* __restrict__ fcb, float* __restrict__ out) {
    __shared__ float zsh[HD][4];       // [k][g]
    __shared__ float psum[2][4][HD];   // [khalf][g][row]
    __shared__ float redsh[2][2][4];   // [q][e][wave-in-half]
    __shared__ float actflag[4];

    const int tid = threadIdx.x;
    const int row = tid & 255;
    const int q   = tid >> 8;          // k-half; owns batch elems g = 2q, 2q+1

    const int b0  = blockIdx.x * 4;

    float bset[4];
    bset[0] = ob1[row]; bset[1] = ob2[row]; bset[2] = ob3[row]; bset[3] = ob4[row];

    float y_own[2];
#pragma unroll
    for (int e = 0; e < 2; ++e) y_own[e] = y0_buf[(b0 + 2 * q + e) * HD + row];

    for (int j = 0; j < 4; ++j) {
        float t1v[2], t_s[2], dt_s[2], ysv[2];
        bool act0[2];
#pragma unroll
        for (int e = 0; e < 2; ++e) {
            const int bidx = b0 + 2 * q + e;
            float tt0 = times[(j * BATCH + bidx) * 2 + 0];
            float tt1 = times[(j * BATCH + bidx) * 2 + 1];
            float ds  = doses[j * BATCH + bidx];
            act0[e] = tt0 < tt1;
            ysv[e] = y_own[e];
            y_own[e] += ds;
            t_s[e] = tt0; t1v[e] = tt1;
            dt_s[e] = fmaxf(tt1 - tt0, 1e-6f) * 0.1f;
        }
        zsh[row][2 * q]     = y_own[0];
        zsh[row][2 * q + 1] = y_own[1];
        if (row == 0) {
            actflag[2 * q]     = act0[0] ? 1.f : 0.f;
            actflag[2 * q + 1] = act0[1] ? 1.f : 0.f;
        }
        __syncthreads();
        bool anyact = (actflag[0] + actflag[1] + actflag[2] + actflag[3]) > 0.f;

        float k1[2], k2[2], k3[2], k4[2], k5[2], k6[2], k7[2], y5[2];
        if (anyact) eval_f2(WT, bset, row, q, zsh, psum, k1);   // FSAL seed

        for (int step = 0; step < 32 && anyact; ++step) {
            bool act[2]; float d[2];
#pragma unroll
            for (int e = 0; e < 2; ++e) {
                act[e] = t_s[e] < t1v[e];
                // NaN-propagating clip (matches jnp semantics)
                float dd = dt_s[e];
                if (dd < 0.f) dd = 0.f;
                float rem = t1v[e] - t_s[e];
                if (rem < 0.f) rem = 0.f;
                if (dd > rem) dd = rem;
                d[e] = dd;
            }
#pragma unroll
            for (int e = 0; e < 2; ++e)
                zsh[row][2 * q + e] = y_own[e] + d[e] * (A21f * k1[e]);
            __syncthreads();
            eval_f2(WT, bset, row, q, zsh, psum, k2);
#pragma unroll
            for (int e = 0; e < 2; ++e)
                zsh[row][2 * q + e] = y_own[e] + d[e] * (A31f * k1[e] + A32f * k2[e]);
            __syncthreads();
            eval_f2(WT, bset, row, q, zsh, psum, k3);
#pragma unroll
            for (int e = 0; e < 2; ++e)
                zsh[row][2 * q + e] = y_own[e] + d[e] * (A41f * k1[e] + A42f * k2[e] + A43f * k3[e]);
            __syncthreads();
            eval_f2(WT, bset, row, q, zsh, psum, k4);
#pragma unroll
            for (int e = 0; e < 2; ++e)
                zsh[row][2 * q + e] = y_own[e] + d[e] * (A51f * k1[e] + A52f * k2[e] + A53f * k3[e] + A54f * k4[e]);
            __syncthreads();
            eval_f2(WT, bset, row, q, zsh, psum, k5);
#pragma unroll
            for (int e = 0; e < 2; ++e)
                zsh[row][2 * q + e] = y_own[e] + d[e] * (A61f * k1[e] + A62f * k2[e] + A63f * k3[e] + A64f * k4[e] + A65f * k5[e]);
            __syncthreads();
            eval_f2(WT, bset, row, q, zsh, psum, k6);
#pragma unroll
            for (int e = 0; e < 2; ++e) {
                y5[e] = y_own[e] + d[e] * (BC0f * k1[e] + BC2f * k3[e] + BC3f * k4[e] + BC4f * k5[e] + BC5f * k6[e]);
                zsh[row][2 * q + e] = y5[e];
            }
            __syncthreads();
            eval_f2(WT, bset, row, q, zsh, psum, k7);

            float s[2];
#pragma unroll
            for (int e = 0; e < 2; ++e) {
                float err = d[e] * (EC0f * k1[e] + EC2f * k3[e] + EC3f * k4[e] + EC4f * k5[e] + EC6f * k7[e] + EC5f * k6[e]);
                float sc = 1e-6f + 1e-3f * fmaxf(fabsf(y_own[e]), fabsf(y5[e]));
                float r = err / sc;
                s[e] = r * r;
            }
#pragma unroll
            for (int off = 32; off; off >>= 1) {
                s[0] += __shfl_xor(s[0], off, 64);
                s[1] += __shfl_xor(s[1], off, 64);
            }
            if ((tid & 63) == 0) {
                redsh[q][0][(tid >> 6) & 3] = s[0];
                redsh[q][1][(tid >> 6) & 3] = s[1];
            }
            __syncthreads();
#pragma unroll
            for (int e = 0; e < 2; ++e) {
                float tot = (redsh[q][e][0] + redsh[q][e][1]) + (redsh[q][e][2] + redsh[q][e][3]);
                float en = sqrtf(tot * (1.0f / HD));
                bool accg = (en <= 1.0f) && act[e];
                if (accg) { y_own[e] = y5[e]; t_s[e] = t_s[e] + d[e]; k1[e] = k7[e]; }  // FSAL
                float fac = 0.9f * powf(en + 1e-10f, -0.2f);
                if (fac < 0.2f) fac = 0.2f;
                if (fac > 10.f) fac = 10.f;
                if (act[e]) dt_s[e] = fmaxf(d[e], 1e-8f) * fac;
            }
            if (row == 0) {
                actflag[2 * q]     = (t_s[0] < t1v[0]) ? 1.f : 0.f;
                actflag[2 * q + 1] = (t_s[1] < t1v[1]) ? 1.f : 0.f;
            }
            __syncthreads();
            anyact = (actflag[0] + actflag[1] + actflag[2] + actflag[3]) > 0.f;
        }
#pragma unroll
        for (int e = 0; e < 2; ++e) y_own[e] = act0[e] ? y_own[e] : ysv[e];
    }

    // final FC: out[b] = y . fcW[0:256] + meta . fcW[256:260] + fcb
    float part[2];
#pragma unroll
    for (int e = 0; e < 2; ++e) part[e] = y_own[e] * fcW[row];
#pragma unroll
    for (int off = 32; off; off >>= 1) {
        part[0] += __shfl_xor(part[0], off, 64);
        part[1] += __shfl_xor(part[1], off, 64);
    }
    if ((tid & 63) == 0) {
        redsh[q][0][(tid >> 6) & 3] = part[0];
        redsh[q][1][(tid >> 6) & 3] = part[1];
    }
    __syncthreads();
    if (row == 0) {
#pragma unroll
        for (int e = 0; e < 2; ++e) {
            const int bidx = b0 + 2 * q + e;
            float v = (redsh[q][e][0] + redsh[q][e][1]) + (redsh[q][e][2] + redsh[q][e][3]);
#pragma unroll
            for (int m = 0; m < MMETA; ++m) v += meta[bidx * MMETA + m] * fcW[HD + m];
            out[bidx] = v + fcb[0];
        }
    }
}

extern "C" void kernel_launch(void* const* d_in, const int* in_sizes, int n_in,
                              void* d_out, int out_size, void* d_ws, size_t ws_size,
                              hipStream_t stream) {
    const float* x     = (const float*)d_in[0];
    const float* meta  = (const float*)d_in[1];
    const float* eps   = (const float*)d_in[2];
    const float* times = (const float*)d_in[3];
    const float* doses = (const float*)d_in[4];
    const float* Wih   = (const float*)d_in[5];
    const float* Whh   = (const float*)d_in[6];
    const float* bih   = (const float*)d_in[7];
    const float* bhh   = (const float*)d_in[8];
    const float* eW1   = (const float*)d_in[9];
    const float* eb1   = (const float*)d_in[10];
    const float* eW2   = (const float*)d_in[11];
    const float* eb2   = (const float*)d_in[12];
    const float* oW1   = (const float*)d_in[13];
    const float* ob1   = (const float*)d_in[14];
    const float* oW2   = (const float*)d_in[15];
    const float* ob2   = (const float*)d_in[16];
    const float* oW3   = (const float*)d_in[17];
    const float* ob3   = (const float*)d_in[18];
    const float* oW4   = (const float*)d_in[19];
    const float* ob4   = (const float*)d_in[20];
    const float* fcW   = (const float*)d_in[21];
    const float* fcb   = (const float*)d_in[22];

    float* ws   = (float*)d_ws;
    float* WihT = ws;             // [8][768]      6144
    float* WhhT = WihT + 6144;    // [256][768]    196608
    float* eW1T = WhhT + 196608;  // [256][256]    65536
    float* eW2T = eW1T + 65536;   // [256][512]    131072
    float* oWT  = eW2T + 131072;  // [4][256][256] 262144
    float* hbuf = oWT + 262144;   // [1024][256]   262144
    float* y0b  = hbuf + 262144;  // [1024][256]   262144

    transpose_kernel<<<dim3(1, 768), 256, 0, stream>>>(Wih, WihT, 768, 8);
    transpose_kernel<<<dim3(1, 768), 256, 0, stream>>>(Whh, WhhT, 768, 256);
    transpose_kernel<<<dim3(1, 256), 256, 0, stream>>>(eW1, eW1T, 256, 256);
    transpose_kernel<<<dim3(1, 512), 256, 0, stream>>>(eW2, eW2T, 512, 256);
    transpose_kernel<<<dim3(1, 256), 256, 0, stream>>>(oW1, oWT, 256, 256);
    transpose_kernel<<<dim3(1, 256), 256, 0, stream>>>(oW2, oWT + 65536, 256, 256);
    transpose_kernel<<<dim3(1, 256), 256, 0, stream>>>(oW3, oWT + 131072, 256, 256);
    transpose_kernel<<<dim3(1, 256), 256, 0, stream>>>(oW4, oWT + 196608, 256, 256);

    gru_kernel<<<BATCH / 4, 768, 0, stream>>>(x, meta, WihT, WhhT, bih, bhh, hbuf);
    enc_kernel<<<BATCH / 8, 256, 0, stream>>>(hbuf, eps, eW1T, eb1, eW2T, eb2, y0b);
    ode_kernel<<<BATCH / 4, 512, 0, stream>>>(y0b, times, doses, oWT, ob1, ob2, ob3, ob4,
                                              meta, fcW, fcb, (float*)d_out);
}

// Round 4
// 2583.192 us; speedup vs baseline: 6.6827x; 1.0483x over previous
//
#include <hip/hip_runtime.h>
#include <math.h>

#define HD 256
#define BATCH 1024
#define NSTEPS 64
#define DIN 4
#define MMETA 4

#define F(x) ((float)(x))
#define A21f F(0.2)
#define A31f F(3.0/40.0)
#define A32f F(9.0/40.0)
#define A41f F(44.0/45.0)
#define A42f F(-56.0/15.0)
#define A43f F(32.0/9.0)
#define A51f F(19372.0/6561.0)
#define A52f F(-25360.0/2187.0)
#define A53f F(64448.0/6561.0)
#define A54f F(-212.0/729.0)
#define A61f F(9017.0/3168.0)
#define A62f F(-355.0/33.0)
#define A63f F(46732.0/5247.0)
#define A64f F(49.0/176.0)
#define A65f F(-5103.0/18656.0)
#define BC0f F(35.0/384.0)
#define BC2f F(500.0/1113.0)
#define BC3f F(125.0/192.0)
#define BC4f F(-2187.0/6784.0)
#define BC5f F(11.0/84.0)
#define EC0f F(35.0/384.0 - 5179.0/57600.0)
#define EC2f F(500.0/1113.0 - 7571.0/16695.0)
#define EC3f F(125.0/192.0 - 393.0/640.0)
#define EC4f F(-2187.0/6784.0 + 92097.0/339200.0)
#define EC5f F(11.0/84.0 - 187.0/2100.0)
#define EC6f F(-1.0/40.0)

#define SELU_SCALE 1.0507009873554805f
#define SELU_ALPHA 1.6732632423543772f

// ---------------- generic transpose: in[R][C] -> out[C][R] ----------------
__global__ void transpose_kernel(const float* __restrict__ in, float* __restrict__ out,
                                 int R, int C) {
    int c = blockIdx.x * 256 + threadIdx.x;
    int r = blockIdx.y;
    if (c < C) out[c * R + r] = in[r * C + c];
}

// ---- pack k-pairs to bf16: in f32 [R][C] -> out u32 [C/2][R] -------------
// out[kp*R + r] = (bf16(in[r][2kp+1]) << 16) | bf16(in[r][2kp]), RNE rounding
__global__ void pack_bf16_kernel(const float* __restrict__ in, unsigned* __restrict__ out,
                                 int R, int C) {
    int r = blockIdx.x * 256 + threadIdx.x;
    int kp = blockIdx.y;
    if (r < R) {
        unsigned ua = __float_as_uint(in[r * C + 2 * kp]);
        unsigned ub = __float_as_uint(in[r * C + 2 * kp + 1]);
        ua = (ua + 0x7fffu + ((ua >> 16) & 1u)) >> 16;
        ub = (ub + 0x7fffu + ((ub >> 16) & 1u)) >> 16;
        out[kp * R + r] = (ub << 16) | ua;
    }
}

// ---------------- ODE partial dot: 128 k (64 bf16 pairs), 4 elems ---------
// wp = WP + L*32768 + q*64*HD + row  (u32 layout: [kp][out_row])
__device__ __forceinline__ void partial128_bf16(const unsigned* __restrict__ wp,
                                                const float (*zsh)[4], int k0,
                                                float (&acc)[4]) {
    unsigned wA[8], wB[8];
#pragma unroll
    for (int u = 0; u < 8; ++u) wA[u] = wp[u * HD];
#pragma unroll
    for (int u = 0; u < 8; ++u) wB[u] = wp[(8 + u) * HD];
    acc[0] = 0.f; acc[1] = 0.f; acc[2] = 0.f; acc[3] = 0.f;
    for (int kp = 0; kp < 64; kp += 8) {
        unsigned wC[8];
        if (kp < 48) {
#pragma unroll
            for (int u = 0; u < 8; ++u) wC[u] = wp[(kp + 16 + u) * HD];
        }
#pragma unroll
        for (int u = 0; u < 8; ++u) {
            const unsigned w = wA[u];
            const float w0 = __uint_as_float(w << 16);          // weight k = 2(kp+u)
            const float w1 = __uint_as_float(w & 0xffff0000u);  // weight k = 2(kp+u)+1
            const int k = k0 + 2 * (kp + u);
            const float4 za = *(const float4*)(&zsh[k][0]);
            const float4 zb = *(const float4*)(&zsh[k + 1][0]);
            acc[0] = fmaf(w0, za.x, acc[0]);
            acc[1] = fmaf(w0, za.y, acc[1]);
            acc[2] = fmaf(w0, za.z, acc[2]);
            acc[3] = fmaf(w0, za.w, acc[3]);
            acc[0] = fmaf(w1, zb.x, acc[0]);
            acc[1] = fmaf(w1, zb.y, acc[1]);
            acc[2] = fmaf(w1, zb.z, acc[2]);
            acc[3] = fmaf(w1, zb.w, acc[3]);
        }
#pragma unroll
        for (int u = 0; u < 8; ++u) { wA[u] = wB[u]; if (kp < 48) wB[u] = wC[u]; }
    }
}

// 4-layer MLP eval; thread (row,q) gets outputs for batch elems g=2q, 2q+1.
// Caller has written zsh (all 4 g) and issued a barrier.
__device__ __forceinline__ void eval_f2(const unsigned* __restrict__ WPb,
                                        const float (&bset)[4],
                                        int row, int q,
                                        float (*zsh)[4],
                                        float (*psum)[4][HD],
                                        float (&vout)[2]) {
#pragma unroll
    for (int L = 0; L < 4; ++L) {
        float acc[4];
        partial128_bf16(WPb + L * 32768 + q * 64 * HD + row, zsh, q * 128, acc);
        psum[q][0][row] = acc[0];
        psum[q][1][row] = acc[1];
        psum[q][2][row] = acc[2];
        psum[q][3][row] = acc[3];
        __syncthreads();
        float v0 = (psum[0][2 * q][row]     + psum[1][2 * q][row])     + bset[L];
        float v1 = (psum[0][2 * q + 1][row] + psum[1][2 * q + 1][row]) + bset[L];
        if (L < 3) {
            float a0 = v0 > 0.f ? SELU_SCALE * v0 : SELU_SCALE * SELU_ALPHA * expm1f(v0);
            float a1 = v1 > 0.f ? SELU_SCALE * v1 : SELU_SCALE * SELU_ALPHA * expm1f(v1);
            zsh[row][2 * q]     = a0;
            zsh[row][2 * q + 1] = a1;
            __syncthreads();
        } else {
            vout[0] = v0; vout[1] = v1;
        }
    }
}

// ---------------- GRU: 256 blocks (G=4), 768 threads, bf16 Whh ------------
__global__ __launch_bounds__(768, 2) void gru_kernel(
    const float* __restrict__ x, const float* __restrict__ meta,
    const float* __restrict__ WihT, const unsigned* __restrict__ WhhP,
    const float* __restrict__ bih, const float* __restrict__ bhh,
    float* __restrict__ h_out) {
    __shared__ float hsh[HD][4];     // [k][g], b128 broadcast reads
    __shared__ float xmsh[8][4];
    __shared__ float gsa[4][768];    // [g][gate_row]: (r,z) pre-act; [512+]: inn
    __shared__ float gsb[4][HD];     // [g][row]: hn part for n-gate

    const int tid = threadIdx.x;     // gate row 0..767
    const int b0  = blockIdx.x * 4;
    const float bi = bih[tid];
    const float bh = bhh[tid];

    float h_own[4];
    if (tid < HD) {
#pragma unroll
        for (int g = 0; g < 4; ++g) { h_own[g] = 0.f; hsh[tid][g] = 0.f; }
    }

    for (int n = 0; n < NSTEPS; ++n) {
        if (tid < 32) {
            int c = tid & 7, gg = tid >> 3;
            xmsh[c][gg] = (c < 4) ? x[((b0 + gg) * NSTEPS + n) * DIN + c]
                                  : meta[(b0 + gg) * MMETA + (c - 4)];
        }
        __syncthreads();   // xm + hsh ready

        float ai[4], ah[4];
#pragma unroll
        for (int g = 0; g < 4; ++g) { ai[g] = bi; ah[g] = bh; }
#pragma unroll
        for (int c = 0; c < 8; ++c) {
            float w = WihT[c * 768 + tid];
            const float4 x4 = *(const float4*)(&xmsh[c][0]);
            ai[0] = fmaf(w, x4.x, ai[0]); ai[1] = fmaf(w, x4.y, ai[1]);
            ai[2] = fmaf(w, x4.z, ai[2]); ai[3] = fmaf(w, x4.w, ai[3]);
        }
        {
            const unsigned* wp = WhhP + tid;
            unsigned wA[8], wB[8];
#pragma unroll
            for (int u = 0; u < 8; ++u) wA[u] = wp[u * 768];
#pragma unroll
            for (int u = 0; u < 8; ++u) wB[u] = wp[(8 + u) * 768];
            for (int kp = 0; kp < 128; kp += 8) {
                unsigned wC[8];
                if (kp < 112) {
#pragma unroll
                    for (int u = 0; u < 8; ++u) wC[u] = wp[(kp + 16 + u) * 768];
                }
#pragma unroll
                for (int u = 0; u < 8; ++u) {
                    const unsigned w = wA[u];
                    const float w0 = __uint_as_float(w << 16);
                    const float w1 = __uint_as_float(w & 0xffff0000u);
                    const int k = 2 * (kp + u);
                    const float4 h4a = *(const float4*)(&hsh[k][0]);
                    const float4 h4b = *(const float4*)(&hsh[k + 1][0]);
                    ah[0] = fmaf(w0, h4a.x, ah[0]); ah[1] = fmaf(w0, h4a.y, ah[1]);
                    ah[2] = fmaf(w0, h4a.z, ah[2]); ah[3] = fmaf(w0, h4a.w, ah[3]);
                    ah[0] = fmaf(w1, h4b.x, ah[0]); ah[1] = fmaf(w1, h4b.y, ah[1]);
                    ah[2] = fmaf(w1, h4b.z, ah[2]); ah[3] = fmaf(w1, h4b.w, ah[3]);
                }
#pragma unroll
                for (int u = 0; u < 8; ++u) { wA[u] = wB[u]; if (kp < 112) wB[u] = wC[u]; }
            }
        }
        if (tid < 512) {
#pragma unroll
            for (int g = 0; g < 4; ++g) gsa[g][tid] = ai[g] + ah[g];
        } else {
#pragma unroll
            for (int g = 0; g < 4; ++g) { gsa[g][tid] = ai[g]; gsb[g][tid - 512] = ah[g]; }
        }
        __syncthreads();   // gates ready; all hsh/xm reads done

        if (tid < HD) {
#pragma unroll
            for (int g = 0; g < 4; ++g) {
                float av  = gsa[g][tid];
                float zv  = gsa[g][tid + 256];
                float niv = gsa[g][tid + 512];
                float nhv = gsb[g][tid];
                float rr = 1.f / (1.f + expf(-av));
                float zz = 1.f / (1.f + expf(-zv));
                float nn = tanhf(niv + rr * nhv);
                h_own[g] = (1.f - zz) * nn + zz * h_own[g];
                hsh[tid][g] = h_own[g];
            }
        }
        // next-iteration top barrier orders hsh writes vs matvec reads
    }
    if (tid < HD) {
#pragma unroll
        for (int g = 0; g < 4; ++g) h_out[(b0 + g) * HD + tid] = h_own[g];
    }
}

// ---------------- encoder + reparameterization (G=8, 128 blocks) ----------
__global__ __launch_bounds__(256) void enc_kernel(
    const float* __restrict__ h_buf, const float* __restrict__ eps,
    const float* __restrict__ W1T, const float* __restrict__ b1,
    const float* __restrict__ W2T, const float* __restrict__ b2,
    float* __restrict__ y0_buf) {
    __shared__ float zsh[HD][8];
    const int tid = threadIdx.x;
    const int b0 = blockIdx.x * 8;
#pragma unroll
    for (int g = 0; g < 8; ++g) zsh[tid][g] = h_buf[(b0 + g) * HD + tid];
    __syncthreads();
    float acc[8];
    {
        float bb = b1[tid];
#pragma unroll
        for (int g = 0; g < 8; ++g) acc[g] = bb;
        for (int k = 0; k < HD; k += 4) {
#pragma unroll
            for (int u = 0; u < 4; ++u) {
                float w = W1T[(k + u) * HD + tid];
                const float4 za = *(const float4*)(&zsh[k + u][0]);
                const float4 zb = *(const float4*)(&zsh[k + u][4]);
                acc[0] = fmaf(w, za.x, acc[0]); acc[1] = fmaf(w, za.y, acc[1]);
                acc[2] = fmaf(w, za.z, acc[2]); acc[3] = fmaf(w, za.w, acc[3]);
                acc[4] = fmaf(w, zb.x, acc[4]); acc[5] = fmaf(w, zb.y, acc[5]);
                acc[6] = fmaf(w, zb.z, acc[6]); acc[7] = fmaf(w, zb.w, acc[7]);
            }
        }
    }
    __syncthreads();
#pragma unroll
    for (int g = 0; g < 8; ++g) zsh[tid][g] = fmaxf(acc[g], 0.f);
    __syncthreads();
    float am[8], as[8];
    {
        float bm = b2[tid], bs = b2[tid + HD];
#pragma unroll
        for (int g = 0; g < 8; ++g) { am[g] = bm; as[g] = bs; }
        for (int k = 0; k < HD; k += 4) {
#pragma unroll
            for (int u = 0; u < 4; ++u) {
                float wm = W2T[(k + u) * 512 + tid];
                float ws2 = W2T[(k + u) * 512 + HD + tid];
                const float4 za = *(const float4*)(&zsh[k + u][0]);
                const float4 zb = *(const float4*)(&zsh[k + u][4]);
                am[0] = fmaf(wm, za.x, am[0]); am[1] = fmaf(wm, za.y, am[1]);
                am[2] = fmaf(wm, za.z, am[2]); am[3] = fmaf(wm, za.w, am[3]);
                am[4] = fmaf(wm, zb.x, am[4]); am[5] = fmaf(wm, zb.y, am[5]);
                am[6] = fmaf(wm, zb.z, am[6]); am[7] = fmaf(wm, zb.w, am[7]);
                as[0] = fmaf(ws2, za.x, as[0]); as[1] = fmaf(ws2, za.y, as[1]);
                as[2] = fmaf(ws2, za.z, as[2]); as[3] = fmaf(ws2, za.w, as[3]);
                as[4] = fmaf(ws2, zb.x, as[4]); as[5] = fmaf(ws2, zb.y, as[5]);
                as[6] = fmaf(ws2, zb.z, as[6]); as[7] = fmaf(ws2, zb.w, as[7]);
            }
        }
    }
#pragma unroll
    for (int g = 0; g < 8; ++g)
        y0_buf[(b0 + g) * HD + tid] = eps[(b0 + g) * HD + tid] * as[g] + am[g];
}

// ---------------- dopri5: 256 blocks (G=4), 512 threads, 2-way k-split ----
__global__ __launch_bounds__(512, 2) void ode_kernel(
    const float* __restrict__ y0_buf, const float* __restrict__ times,
    const float* __restrict__ doses, const unsigned* __restrict__ WP,
    const float* __restrict__ ob1, const float* __restrict__ ob2,
    const float* __restrict__ ob3, const float* __restrict__ ob4,
    const float* __restrict__ meta, const float* __restrict__ fcW,
    const float* __restrict__ fcb, float* __restrict__ out) {
    __shared__ float zsh[HD][4];       // [k][g]
    __shared__ float psum[2][4][HD];   // [khalf][g][row]
    __shared__ float redsh[2][2][4];   // [q][e][wave-in-half]
    __shared__ float actflag[4];

    const int tid = threadIdx.x;
    const int row = tid & 255;
    const int q   = tid >> 8;          // k-half; owns batch elems g = 2q, 2q+1

    const int b0  = blockIdx.x * 4;

    float bset[4];
    bset[0] = ob1[row]; bset[1] = ob2[row]; bset[2] = ob3[row]; bset[3] = ob4[row];

    float y_own[2];
#pragma unroll
    for (int e = 0; e < 2; ++e) y_own[e] = y0_buf[(b0 + 2 * q + e) * HD + row];

    for (int j = 0; j < 4; ++j) {
        float t1v[2], t_s[2], dt_s[2], ysv[2];
        bool act0[2];
#pragma unroll
        for (int e = 0; e < 2; ++e) {
            const int bidx = b0 + 2 * q + e;
            float tt0 = times[(j * BATCH + bidx) * 2 + 0];
            float tt1 = times[(j * BATCH + bidx) * 2 + 1];
            float ds  = doses[j * BATCH + bidx];
            act0[e] = tt0 < tt1;
            ysv[e] = y_own[e];
            y_own[e] += ds;
            t_s[e] = tt0; t1v[e] = tt1;
            dt_s[e] = fmaxf(tt1 - tt0, 1e-6f) * 0.1f;
        }
        zsh[row][2 * q]     = y_own[0];
        zsh[row][2 * q + 1] = y_own[1];
        if (row == 0) {
            actflag[2 * q]     = act0[0] ? 1.f : 0.f;
            actflag[2 * q + 1] = act0[1] ? 1.f : 0.f;
        }
        __syncthreads();
        bool anyact = (actflag[0] + actflag[1] + actflag[2] + actflag[3]) > 0.f;

        float k1[2], k2[2], k3[2], k4[2], k5[2], k6[2], k7[2], y5[2];
        if (anyact) eval_f2(WP, bset, row, q, zsh, psum, k1);   // FSAL seed

        for (int step = 0; step < 32 && anyact; ++step) {
            bool act[2]; float d[2];
#pragma unroll
            for (int e = 0; e < 2; ++e) {
                act[e] = t_s[e] < t1v[e];
                // NaN-propagating clip (matches jnp semantics)
                float dd = dt_s[e];
                if (dd < 0.f) dd = 0.f;
                float rem = t1v[e] - t_s[e];
                if (rem < 0.f) rem = 0.f;
                if (dd > rem) dd = rem;
                d[e] = dd;
            }
#pragma unroll
            for (int e = 0; e < 2; ++e)
                zsh[row][2 * q + e] = y_own[e] + d[e] * (A21f * k1[e]);
            __syncthreads();
            eval_f2(WP, bset, row, q, zsh, psum, k2);
#pragma unroll
            for (int e = 0; e < 2; ++e)
                zsh[row][2 * q + e] = y_own[e] + d[e] * (A31f * k1[e] + A32f * k2[e]);
            __syncthreads();
            eval_f2(WP, bset, row, q, zsh, psum, k3);
#pragma unroll
            for (int e = 0; e < 2; ++e)
                zsh[row][2 * q + e] = y_own[e] + d[e] * (A41f * k1[e] + A42f * k2[e] + A43f * k3[e]);
            __syncthreads();
            eval_f2(WP, bset, row, q, zsh, psum, k4);
#pragma unroll
            for (int e = 0; e < 2; ++e)
                zsh[row][2 * q + e] = y_own[e] + d[e] * (A51f * k1[e] + A52f * k2[e] + A53f * k3[e] + A54f * k4[e]);
            __syncthreads();
            eval_f2(WP, bset, row, q, zsh, psum, k5);
#pragma unroll
            for (int e = 0; e < 2; ++e)
                zsh[row][2 * q + e] = y_own[e] + d[e] * (A61f * k1[e] + A62f * k2[e] + A63f * k3[e] + A64f * k4[e] + A65f * k5[e]);
            __syncthreads();
            eval_f2(WP, bset, row, q, zsh, psum, k6);
#pragma unroll
            for (int e = 0; e < 2; ++e) {
                y5[e] = y_own[e] + d[e] * (BC0f * k1[e] + BC2f * k3[e] + BC3f * k4[e] + BC4f * k5[e] + BC5f * k6[e]);
                zsh[row][2 * q + e] = y5[e];
            }
            __syncthreads();
            eval_f2(WP, bset, row, q, zsh, psum, k7);

            float s[2];
#pragma unroll
            for (int e = 0; e < 2; ++e) {
                float err = d[e] * (EC0f * k1[e] + EC2f * k3[e] + EC3f * k4[e] + EC4f * k5[e] + EC5f * k6[e] + EC6f * k7[e]);
                float sc = 1e-6f + 1e-3f * fmaxf(fabsf(y_own[e]), fabsf(y5[e]));
                float r = err / sc;
                s[e] = r * r;
            }
#pragma unroll
            for (int off = 32; off; off >>= 1) {
                s[0] += __shfl_xor(s[0], off, 64);
                s[1] += __shfl_xor(s[1], off, 64);
            }
            if ((tid & 63) == 0) {
                redsh[q][0][(tid >> 6) & 3] = s[0];
                redsh[q][1][(tid >> 6) & 3] = s[1];
            }
            __syncthreads();
#pragma unroll
            for (int e = 0; e < 2; ++e) {
                float tot = (redsh[q][e][0] + redsh[q][e][1]) + (redsh[q][e][2] + redsh[q][e][3]);
                float en = sqrtf(tot * (1.0f / HD));
                bool accg = (en <= 1.0f) && act[e];
                if (accg) { y_own[e] = y5[e]; t_s[e] = t_s[e] + d[e]; k1[e] = k7[e]; }  // FSAL
                float fac = 0.9f * powf(en + 1e-10f, -0.2f);
                if (fac < 0.2f) fac = 0.2f;
                if (fac > 10.f) fac = 10.f;
                if (act[e]) dt_s[e] = fmaxf(d[e], 1e-8f) * fac;
            }
            if (row == 0) {
                actflag[2 * q]     = (t_s[0] < t1v[0]) ? 1.f : 0.f;
                actflag[2 * q + 1] = (t_s[1] < t1v[1]) ? 1.f : 0.f;
            }
            __syncthreads();
            anyact = (actflag[0] + actflag[1] + actflag[2] + actflag[3]) > 0.f;
        }
#pragma unroll
        for (int e = 0; e < 2; ++e) y_own[e] = act0[e] ? y_own[e] : ysv[e];
    }

    // final FC: out[b] = y . fcW[0:256] + meta . fcW[256:260] + fcb
    float part[2];
#pragma unroll
    for (int e = 0; e < 2; ++e) part[e] = y_own[e] * fcW[row];
#pragma unroll
    for (int off = 32; off; off >>= 1) {
        part[0] += __shfl_xor(part[0], off, 64);
        part[1] += __shfl_xor(part[1], off, 64);
    }
    if ((tid & 63) == 0) {
        redsh[q][0][(tid >> 6) & 3] = part[0];
        redsh[q][1][(tid >> 6) & 3] = part[1];
    }
    __syncthreads();
    if (row == 0) {
#pragma unroll
        for (int e = 0; e < 2; ++e) {
            const int bidx = b0 + 2 * q + e;
            float v = (redsh[q][e][0] + redsh[q][e][1]) + (redsh[q][e][2] + redsh[q][e][3]);
#pragma unroll
            for (int m = 0; m < MMETA; ++m) v += meta[bidx * MMETA + m] * fcW[HD + m];
            out[bidx] = v + fcb[0];
        }
    }
}

extern "C" void kernel_launch(void* const* d_in, const int* in_sizes, int n_in,
                              void* d_out, int out_size, void* d_ws, size_t ws_size,
                              hipStream_t stream) {
    const float* x     = (const float*)d_in[0];
    const float* meta  = (const float*)d_in[1];
    const float* eps   = (const float*)d_in[2];
    const float* times = (const float*)d_in[3];
    const float* doses = (const float*)d_in[4];
    const float* Wih   = (const float*)d_in[5];
    const float* Whh   = (const float*)d_in[6];
    const float* bih   = (const float*)d_in[7];
    const float* bhh   = (const float*)d_in[8];
    const float* eW1   = (const float*)d_in[9];
    const float* eb1   = (const float*)d_in[10];
    const float* eW2   = (const float*)d_in[11];
    const float* eb2   = (const float*)d_in[12];
    const float* oW1   = (const float*)d_in[13];
    const float* ob1   = (const float*)d_in[14];
    const float* oW2   = (const float*)d_in[15];
    const float* ob2   = (const float*)d_in[16];
    const float* oW3   = (const float*)d_in[17];
    const float* ob3   = (const float*)d_in[18];
    const float* oW4   = (const float*)d_in[19];
    const float* ob4   = (const float*)d_in[20];
    const float* fcW   = (const float*)d_in[21];
    const float* fcb   = (const float*)d_in[22];

    float* ws   = (float*)d_ws;
    float*    WihT = ws;                          // f32 [8][768]        6144
    unsigned* WhhP = (unsigned*)(ws + 6144);      // u32 [128][768]      98304
    float*    eW1T = ws + 104448;                 // f32 [256][256]      65536
    float*    eW2T = ws + 169984;                 // f32 [256][512]      131072
    unsigned* oWP  = (unsigned*)(ws + 301056);    // u32 [4][128][256]   131072
    float*    hbuf = ws + 432128;                 // f32 [1024][256]     262144
    float*    y0b  = hbuf + 262144;               // f32 [1024][256]     262144

    transpose_kernel<<<dim3(1, 768), 256, 0, stream>>>(Wih, WihT, 768, 8);
    pack_bf16_kernel<<<dim3(3, 128), 256, 0, stream>>>(Whh, WhhP, 768, 256);
    transpose_kernel<<<dim3(1, 256), 256, 0, stream>>>(eW1, eW1T, 256, 256);
    transpose_kernel<<<dim3(1, 512), 256, 0, stream>>>(eW2, eW2T, 512, 256);
    pack_bf16_kernel<<<dim3(1, 128), 256, 0, stream>>>(oW1, oWP,          256, 256);
    pack_bf16_kernel<<<dim3(1, 128), 256, 0, stream>>>(oW2, oWP + 32768,  256, 256);
    pack_bf16_kernel<<<dim3(1, 128), 256, 0, stream>>>(oW3, oWP + 65536,  256, 256);
    pack_bf16_kernel<<<dim3(1, 128), 256, 0, stream>>>(oW4, oWP + 98304,  256, 256);

    gru_kernel<<<BATCH / 4, 768, 0, stream>>>(x, meta, WihT, WhhP, bih, bhh, hbuf);
    enc_kernel<<<BATCH / 8, 256, 0, stream>>>(hbuf, eps, eW1T, eb1, eW2T, eb2, y0b);
    ode_kernel<<<BATCH / 4, 512, 0, stream>>>(y0b, times, doses, oWP, ob1, ob2, ob3, ob4,
                                              meta, fcW, fcb, (float*)d_out);
}